// Round 1
// baseline (8377.695 us; speedup 1.0000x reference)
//
#include <hip/hip_runtime.h>
#include <math.h>

// Problem dims
#define BATCH 16
#define SEQ   2048
#define L_INP 256
#define MENC  512
#define HD    1024
#define FM    4096
// Scan chunking: C chunks of T steps
#define TCH   32
#define NCH   64
#define NROW  (BATCH*NCH)   // 1024 rows in chunk-scan space, row r = c*16 + b

static_assert(TCH * NCH == SEQ, "chunking must cover SEQ");

// GEMM tile config
#define TS 64
#define KT 16
#define LP 68   // padded LDS stride (multiple of 4 -> float4-aligned)

__device__ inline float4 add4(float4 a, float4 b) {
    return make_float4(a.x + b.x, a.y + b.y, a.z + b.z, a.w + b.w);
}

// Generic fp32 tiled GEMM, 64x64 tile, 256 threads, 4x4 per thread.
// MODE 0: OUT = IN@W
// MODE 1: OUT = IN@W + bias
// MODE 2: OUT = relu(IN@W + bias)
// MODE 3: scan step: OUT[r] = IN[r]@W + Bu[burow(r,t)]          (EX = Bu)
// MODE 5: prefix:    OUT[r] = EX[r] + (r>=dshift ? IN[r-dshift]@W : 0)
// MODE 6: scan step + scatter: like 3, also HOUT[burow(r,t)] = result
template<int MODE>
__global__ __launch_bounds__(256)
void gemm_k(const float* __restrict__ IN, const float* __restrict__ W,
            float* __restrict__ OUT, const float* __restrict__ BIAS,
            const float* __restrict__ EX, float* __restrict__ HOUT,
            int M, int N, int K, int ldIN, int t, int dshift)
{
    __shared__ float As[KT][LP];   // A-tile transposed: As[k][row]
    __shared__ float Bs[KT][LP];   // B-tile natural:    Bs[k][col]
    const int tid  = threadIdx.x;
    const int tx   = tid & 15, ty = tid >> 4;
    const int col0 = blockIdx.x * TS;
    const int row0 = blockIdx.y * TS;
    const int la_k = tid & 15, la_r = tid >> 4;   // A loader: k-fast
    const int lb_j = tid & 63, lb_k = tid >> 6;   // B loader: col-fast
    float acc[4][4] = {};

    for (int k0 = 0; k0 < K; k0 += KT) {
        #pragma unroll
        for (int i = 0; i < 4; ++i) {
            int r = la_r + (i << 4);
            int grow = row0 + r;
            float v = 0.f;
            if constexpr (MODE == 5) {
                int srow = grow - dshift;
                if (srow >= 0) v = IN[(long)srow * ldIN + k0 + la_k];
            } else {
                if (grow < M) v = IN[(long)grow * ldIN + k0 + la_k];
            }
            As[la_k][r] = v;
        }
        #pragma unroll
        for (int i = 0; i < 4; ++i) {
            int k = lb_k + (i << 2);
            Bs[k][lb_j] = W[(long)(k0 + k) * N + col0 + lb_j];
        }
        __syncthreads();
        #pragma unroll
        for (int kk = 0; kk < KT; ++kk) {
            float4 av = *(const float4*)&As[kk][ty << 2];
            float4 bv = *(const float4*)&Bs[kk][tx << 2];
            float ar[4] = {av.x, av.y, av.z, av.w};
            float br[4] = {bv.x, bv.y, bv.z, bv.w};
            #pragma unroll
            for (int i = 0; i < 4; ++i)
                #pragma unroll
                for (int j = 0; j < 4; ++j)
                    acc[i][j] = fmaf(ar[i], br[j], acc[i][j]);
        }
        __syncthreads();
    }

    const int jc = col0 + (tx << 2);
    float4 bias4 = make_float4(0.f, 0.f, 0.f, 0.f);
    if constexpr (MODE == 1 || MODE == 2) bias4 = *(const float4*)&BIAS[jc];

    #pragma unroll
    for (int i = 0; i < 4; ++i) {
        int row = row0 + (ty << 2) + i;
        if (row >= M) continue;
        float4 vv = make_float4(acc[i][0], acc[i][1], acc[i][2], acc[i][3]);
        if constexpr (MODE == 1 || MODE == 2) vv = add4(vv, bias4);
        if constexpr (MODE == 2) {
            vv.x = fmaxf(vv.x, 0.f); vv.y = fmaxf(vv.y, 0.f);
            vv.z = fmaxf(vv.z, 0.f); vv.w = fmaxf(vv.w, 0.f);
        }
        long exoff = 0;
        if constexpr (MODE == 3 || MODE == 6) {
            int b = row & 15, c = row >> 4;
            exoff = ((long)(b * SEQ + c * TCH + t) << 10) + jc;  // H_DIM=1024
            vv = add4(vv, *(const float4*)&EX[exoff]);
        }
        if constexpr (MODE == 5) {
            vv = add4(vv, *(const float4*)&EX[(long)row * N + jc]);
        }
        *(float4*)&OUT[(long)row * N + jc] = vv;
        if constexpr (MODE == 6) *(float4*)&HOUT[exoff] = vv;
    }
}

// Pass-1 step 0: L0[r] = Bu[(b, c*T + 0)]
__global__ __launch_bounds__(256)
void gather_bu(const float* __restrict__ Bu, float* __restrict__ L0)
{
    long i = ((long)blockIdx.x * 256 + threadIdx.x) * 4;
    int row = (int)(i >> 10);
    int col = (int)(i & 1023);
    int b = row & 15, c = row >> 4;
    *(float4*)&L0[i] = *(const float4*)&Bu[((long)(b * SEQ + c * TCH) << 10) + col];
}

// Entry states: Eent[r=c*16+b] = (c>0) ? Sfin[(c-1)*16+b] : 0
__global__ __launch_bounds__(256)
void make_entry(const float* __restrict__ S, float* __restrict__ E)
{
    long i = ((long)blockIdx.x * 256 + threadIdx.x) * 4;
    int row = (int)(i >> 10);
    int col = (int)(i & 1023);
    int b = row & 15, c = row >> 4;
    float4 v = make_float4(0.f, 0.f, 0.f, 0.f);
    if (c > 0) v = *(const float4*)&S[(((long)(c - 1) * BATCH + b) << 10) + col];
    *(float4*)&E[i] = v;
}

// z = h_last + residual_last; LayerNorm in double (z ~ 1e27 -> z^2 overflows fp32)
__global__ __launch_bounds__(256)
void ln_k(const float* __restrict__ Sfin, const float* __restrict__ Rlast,
          const float* __restrict__ g, const float* __restrict__ bta,
          float* __restrict__ zout)
{
    __shared__ double red[256];
    int b = blockIdx.x, tid = threadIdx.x;
    const float* h  = Sfin + (((long)(NCH - 1) * BATCH + b) << 10);
    const float* rr = Rlast + b * HD;
    double s = 0.0;
    for (int j = tid; j < HD; j += 256) s += (double)h[j] + (double)rr[j];
    red[tid] = s; __syncthreads();
    for (int o = 128; o > 0; o >>= 1) { if (tid < o) red[tid] += red[tid + o]; __syncthreads(); }
    double mu = red[0] * (1.0 / HD);
    __syncthreads();
    double ss = 0.0;
    for (int j = tid; j < HD; j += 256) {
        double z = (double)h[j] + (double)rr[j] - mu;
        ss += z * z;
    }
    red[tid] = ss; __syncthreads();
    for (int o = 128; o > 0; o >>= 1) { if (tid < o) red[tid] += red[tid + o]; __syncthreads(); }
    double inv = 1.0 / sqrt(red[0] * (1.0 / HD) + 1e-5);
    __syncthreads();
    for (int j = tid; j < HD; j += 256) {
        double z = (double)h[j] + (double)rr[j];
        zout[b * HD + j] = (float)(((z - mu) * inv) * (double)g[j] + (double)bta[j]);
    }
}

extern "C" void kernel_launch(void* const* d_in, const int* in_sizes, int n_in,
                              void* d_out, int out_size, void* d_ws, size_t ws_size,
                              hipStream_t stream)
{
    const float* x     = (const float*)d_in[0];
    const float* W_enc = (const float*)d_in[1];
    const float* b_enc = (const float*)d_in[2];
    const float* W_B   = (const float*)d_in[3];
    const float* A     = (const float*)d_in[4];
    const float* W_res = (const float*)d_in[5];
    const float* b_res = (const float*)d_in[6];
    const float* ln_g  = (const float*)d_in[7];
    const float* ln_b  = (const float*)d_in[8];
    const float* W1    = (const float*)d_in[9];
    const float* b1    = (const float*)d_in[10];
    const float* W2    = (const float*)d_in[11];
    const float* b2    = (const float*)d_in[12];

    float* out0 = (float*)d_out;                 // (16,1024)
    float* Hout = out0 + (long)BATCH * HD;       // (16,2048,1024) H_seq_pre

    // Workspace layout (floats). E lives in the Hout region (free until pass 3).
    float* w = (float*)d_ws;
    float* Bu = w;                w += (long)BATCH * SEQ * HD;     // 33.55M
    float* P[10];
    for (int i = 0; i < 10; ++i) { P[i] = w; w += (long)HD * HD; } // A^2..A^1024
    float* Lb0  = w;              w += (long)NROW * HD;
    float* Lb1  = w;              w += (long)NROW * HD;
    float* Sb0  = w;              w += (long)NROW * HD;
    float* Sb1  = w;              w += (long)NROW * HD;
    float* Eent = w;              w += (long)NROW * HD;
    float* Rlast = w;             w += (long)BATCH * HD;
    float* zln   = w;             w += (long)BATCH * HD;
    float* t1    = w;             w += (long)BATCH * FM;
    float* E = Hout;              // (32768,512) fits in first half of Hout

    const long MS = (long)BATCH * SEQ;  // 32768
    dim3 blk(256);

    // 1) E = x @ W_enc + b_enc     (32768,256)@(256,512)
    gemm_k<1><<<dim3(MENC / TS, MS / TS), blk, 0, stream>>>(
        x, W_enc, E, b_enc, nullptr, nullptr, (int)MS, MENC, L_INP, L_INP, 0, 0);
    // 2) Bu = E @ W_B              (32768,512)@(512,1024)
    gemm_k<0><<<dim3(HD / TS, MS / TS), blk, 0, stream>>>(
        E, W_B, Bu, nullptr, nullptr, nullptr, (int)MS, HD, MENC, MENC, 0, 0);

    // 3) Matrix powers by squaring: P[0]=A^2 ... P[4]=A^32=G ... P[9]=A^1024=G^32
    {
        const float* prev = A;
        for (int i = 0; i < 10; ++i) {
            gemm_k<0><<<dim3(HD / TS, HD / TS), blk, 0, stream>>>(
                prev, prev, P[i], nullptr, nullptr, nullptr, HD, HD, HD, HD, 0, 0);
            prev = P[i];
        }
    }

    // 4) Pass 1: local chunk scans from zero, keep only final state per chunk
    gather_bu<<<dim3(NROW * HD / 1024), blk, 0, stream>>>(Bu, Lb0);
    float* cur = Lb0; float* nxt = Lb1;
    for (int t = 1; t < TCH; ++t) {
        gemm_k<3><<<dim3(HD / TS, NROW / TS), blk, 0, stream>>>(
            cur, A, nxt, nullptr, Bu, nullptr, NROW, HD, HD, HD, t, 0);
        float* tmp = cur; cur = nxt; nxt = tmp;
    }
    float* Lend = cur;   // = Lb1 (TCH-1 = 31 steps, odd)

    // 5) Hillis-Steele prefix over chunk-end states: S_c += S_{c-d} @ G^d
    float* pin = Lend; float* pa = Sb0; float* pb = Sb1;
    for (int i = 0; i < 6; ++i) {
        int d = 1 << i;
        gemm_k<5><<<dim3(HD / TS, NROW / TS), blk, 0, stream>>>(
            pin, P[4 + i], pa, nullptr, pin, nullptr, NROW, HD, HD, HD, 0, d * BATCH);
        pin = pa; float* tmp = pa; pa = pb; pb = tmp;
    }
    float* Sfin = pin;   // Sb1: S_c = state at end of chunk c

    // 6) Entry states per chunk
    make_entry<<<dim3(NROW * HD / 1024), blk, 0, stream>>>(Sfin, Eent);

    // 7) Pass 3: re-run chunk scans seeded with entry states; scatter all states
    cur = Eent; nxt = Lb0;
    for (int t = 0; t < TCH; ++t) {
        gemm_k<6><<<dim3(HD / TS, NROW / TS), blk, 0, stream>>>(
            cur, A, nxt, nullptr, Bu, Hout, NROW, HD, HD, HD, t, 0);
        cur = nxt; nxt = (cur == Lb0) ? Lb1 : Lb0;
    }

    // 8) Last-token epilogue: residual, LN (double), MLP
    gemm_k<1><<<dim3(HD / TS, 1), blk, 0, stream>>>(
        x + (long)(SEQ - 1) * L_INP, W_res, Rlast, b_res, nullptr, nullptr,
        BATCH, HD, L_INP, SEQ * L_INP, 0, 0);
    ln_k<<<dim3(BATCH), blk, 0, stream>>>(Sfin, Rlast, ln_g, ln_b, zln);
    gemm_k<2><<<dim3(FM / TS, 1), blk, 0, stream>>>(
        zln, W1, t1, b1, nullptr, nullptr, BATCH, FM, HD, HD, 0, 0);
    gemm_k<1><<<dim3(HD / TS, 1), blk, 0, stream>>>(
        t1, W2, out0, b2, nullptr, nullptr, BATCH, HD, FM, FM, 0, 0);
}

// Round 3
// 5074.572 us; speedup vs baseline: 1.6509x; 1.6509x over previous
//
#include <hip/hip_runtime.h>
#include <math.h>

// Problem dims
#define BATCH 16
#define SEQ   2048
#define L_INP 256
#define MENC  512
#define HD    1024
#define FM    4096
// Scan chunking: C chunks of T steps
#define TCH   16
#define NCH   128
#define NROW  (BATCH*NCH)   // 2048 rows, row r = c*16 + b

static_assert(TCH * NCH == SEQ, "chunking must cover SEQ");

// GEMM tile config
#define TS 64
#define KT 16
#define LP 68   // padded LDS stride

__device__ inline float4 add4(float4 a, float4 b) {
    return make_float4(a.x + b.x, a.y + b.y, a.z + b.z, a.w + b.w);
}

// Generic fp32 tiled GEMM, 64x64 tile, 256 threads, 4x4 per thread.
// MODE 0: OUT = IN@W
// MODE 1: OUT = IN@W + bias
// MODE 2: OUT = relu(IN@W + bias)
// MODE 5: prefix:  OUT[r] = EX[r] + (r>=dshift ? IN[r-dshift]@W : 0)
// MODE 6: scan step + scatter: OUT[r] = IN[r]@W + Bu[burow(r,t)]; HOUT[burow(r,t)] = same
// MODE 7: pass3: HOUT[burow(r, z)] += (r>=16 ? IN[r-16] @ A^(z+1) : 0); z=blockIdx.z
//         (entry state passes through A BEFORE bu_0: h_{t0+z} = E@A^{z+1} + L[c,z])
// MODE 8: batched powers: OUT(base+(dshift+z)) = IN(base+(t+z)) @ W   (slots of HD*HD)
template<int MODE>
__global__ __launch_bounds__(256)
void gemm_k(const float* __restrict__ IN, const float* __restrict__ W,
            float* __restrict__ OUT, const float* __restrict__ BIAS,
            const float* __restrict__ EX, float* __restrict__ HOUT,
            int M, int N, int K, int ldIN, int t, int dshift)
{
    const int z = blockIdx.z;
    if constexpr (MODE == 8) {
        IN  += ((long)(t + z)) << 20;       // HD*HD = 1<<20
        OUT += ((long)(dshift + z)) << 20;
    }
    if constexpr (MODE == 7) {
        W += ((long)z) << 20;               // apw[z] = A^(z+1)
    }

    const int tid  = threadIdx.x;
    const int tx   = tid & 15, ty = tid >> 4;
    const int col0 = blockIdx.x * TS;
    const int row0 = blockIdx.y * TS;
    const int jc   = col0 + (tx << 2);

    __shared__ float As[KT][LP];
    __shared__ float Bs[KT][LP];
    const int la_k = tid & 15, la_r = tid >> 4;
    const int lb_j = tid & 63, lb_k = tid >> 6;
    float acc[4][4] = {};

    for (int k0 = 0; k0 < K; k0 += KT) {
        #pragma unroll
        for (int i = 0; i < 4; ++i) {
            int r = la_r + (i << 4);
            int grow = row0 + r;
            float v = 0.f;
            if constexpr (MODE == 5 || MODE == 7) {
                int srow = grow - dshift;
                if (srow >= 0) v = IN[(long)srow * ldIN + k0 + la_k];
            } else {
                if (grow < M) v = IN[(long)grow * ldIN + k0 + la_k];
            }
            As[la_k][r] = v;
        }
        #pragma unroll
        for (int i = 0; i < 4; ++i) {
            int k = lb_k + (i << 2);
            Bs[k][lb_j] = W[(long)(k0 + k) * N + col0 + lb_j];
        }
        __syncthreads();
        #pragma unroll
        for (int kk = 0; kk < KT; ++kk) {
            float4 av = *(const float4*)&As[kk][ty << 2];
            float4 bv = *(const float4*)&Bs[kk][tx << 2];
            float ar[4] = {av.x, av.y, av.z, av.w};
            float br[4] = {bv.x, bv.y, bv.z, bv.w};
            #pragma unroll
            for (int i = 0; i < 4; ++i)
                #pragma unroll
                for (int j = 0; j < 4; ++j)
                    acc[i][j] = fmaf(ar[i], br[j], acc[i][j]);
        }
        __syncthreads();
    }

    float4 bias4 = make_float4(0.f, 0.f, 0.f, 0.f);
    if constexpr (MODE == 1 || MODE == 2) bias4 = *(const float4*)&BIAS[jc];

    #pragma unroll
    for (int i = 0; i < 4; ++i) {
        int row = row0 + (ty << 2) + i;
        if (row >= M) continue;
        float4 vv = make_float4(acc[i][0], acc[i][1], acc[i][2], acc[i][3]);
        if constexpr (MODE == 1 || MODE == 2) vv = add4(vv, bias4);
        if constexpr (MODE == 2) {
            vv.x = fmaxf(vv.x, 0.f); vv.y = fmaxf(vv.y, 0.f);
            vv.z = fmaxf(vv.z, 0.f); vv.w = fmaxf(vv.w, 0.f);
        }
        if constexpr (MODE == 6) {
            int b = row & 15, c = row >> 4;
            long exoff = ((long)(b * SEQ + c * TCH + t) << 10) + jc;
            vv = add4(vv, *(const float4*)&EX[exoff]);
            *(float4*)&OUT[(long)row * N + jc] = vv;
            *(float4*)&HOUT[exoff] = vv;
        } else if constexpr (MODE == 7) {
            int b = row & 15, c = row >> 4;
            long exoff = ((long)(b * SEQ + c * TCH + z) << 10) + jc;
            float4 h = *(const float4*)&HOUT[exoff];
            *(float4*)&HOUT[exoff] = add4(h, vv);
        } else {
            if constexpr (MODE == 5)
                vv = add4(vv, *(const float4*)&EX[(long)row * N + jc]);
            *(float4*)&OUT[(long)row * N + jc] = vv;
        }
    }
}

// t=0 of pass 1: L0[r] = Bu[(b, c*T)]; also scatter into Hout
__global__ __launch_bounds__(256)
void gather_bu(const float* __restrict__ Bu, float* __restrict__ L0,
               float* __restrict__ Hout)
{
    long i = ((long)blockIdx.x * 256 + threadIdx.x) * 4;
    int row = (int)(i >> 10);
    int col = (int)(i & 1023);
    int b = row & 15, c = row >> 4;
    long off = ((long)(b * SEQ + c * TCH) << 10) + col;
    float4 v = *(const float4*)&Bu[off];
    *(float4*)&L0[i] = v;
    *(float4*)&Hout[off] = v;
}

// simple vector copy (A -> apw[0])
__global__ __launch_bounds__(256)
void copy4(const float* __restrict__ src, float* __restrict__ dst)
{
    long i = ((long)blockIdx.x * 256 + threadIdx.x) * 4;
    *(float4*)&dst[i] = *(const float4*)&src[i];
}

// z = h_last + residual_last; LayerNorm in double (z ~ 1e27 -> z^2 overflows fp32)
__global__ __launch_bounds__(256)
void ln_k(const float* __restrict__ Sfin, const float* __restrict__ Rlast,
          const float* __restrict__ g, const float* __restrict__ bta,
          float* __restrict__ zout)
{
    __shared__ double red[256];
    int b = blockIdx.x, tid = threadIdx.x;
    const float* h  = Sfin + (((long)(NCH - 1) * BATCH + b) << 10);
    const float* rr = Rlast + b * HD;
    double s = 0.0;
    for (int j = tid; j < HD; j += 256) s += (double)h[j] + (double)rr[j];
    red[tid] = s; __syncthreads();
    for (int o = 128; o > 0; o >>= 1) { if (tid < o) red[tid] += red[tid + o]; __syncthreads(); }
    double mu = red[0] * (1.0 / HD);
    __syncthreads();
    double ss = 0.0;
    for (int j = tid; j < HD; j += 256) {
        double zz = (double)h[j] + (double)rr[j] - mu;
        ss += zz * zz;
    }
    red[tid] = ss; __syncthreads();
    for (int o = 128; o > 0; o >>= 1) { if (tid < o) red[tid] += red[tid + o]; __syncthreads(); }
    double inv = 1.0 / sqrt(red[0] * (1.0 / HD) + 1e-5);
    __syncthreads();
    for (int j = tid; j < HD; j += 256) {
        double zz = (double)h[j] + (double)rr[j];
        zout[b * HD + j] = (float)(((zz - mu) * inv) * (double)g[j] + (double)bta[j]);
    }
}

extern "C" void kernel_launch(void* const* d_in, const int* in_sizes, int n_in,
                              void* d_out, int out_size, void* d_ws, size_t ws_size,
                              hipStream_t stream)
{
    const float* x     = (const float*)d_in[0];
    const float* W_enc = (const float*)d_in[1];
    const float* b_enc = (const float*)d_in[2];
    const float* W_B   = (const float*)d_in[3];
    const float* A     = (const float*)d_in[4];
    const float* W_res = (const float*)d_in[5];
    const float* b_res = (const float*)d_in[6];
    const float* ln_g  = (const float*)d_in[7];
    const float* ln_b  = (const float*)d_in[8];
    const float* W1    = (const float*)d_in[9];
    const float* b1    = (const float*)d_in[10];
    const float* W2    = (const float*)d_in[11];
    const float* b2    = (const float*)d_in[12];

    float* out0 = (float*)d_out;                 // (16,1024)
    float* Hout = out0 + (long)BATCH * HD;       // (16,2048,1024) H_seq_pre

    const long M2 = (long)HD * HD;               // 1<<20
    float* w = (float*)d_ws;
    float* Bu   = w;  w += (long)BATCH * SEQ * HD;   // 33.55M floats
    float* apw  = w;  w += 16 * M2;                  // apw slot i = A^(i+1), i=0..15
    float* GP   = w;  w += 6 * M2;                   // GP[i] = A^(32<<i)
    float* Wf   = w;  w += (long)L_INP * HD;         // fused W_enc@W_B
    float* bf   = w;  w += HD;                       // fused bias
    float* L0   = w;  w += (long)NROW * HD;
    float* L1   = w;  w += (long)NROW * HD;
    float* S0   = w;  w += (long)NROW * HD;
    float* Rlast = w; w += (long)BATCH * HD;
    float* zln   = w; w += (long)BATCH * HD;
    float* t1    = w; w += (long)BATCH * FM;

    dim3 blk(256);
    const long MS = (long)BATCH * SEQ;  // 32768

    // --- Encoder (fused): Bu = x @ (W_enc@W_B) + b_enc@W_B ---
    gemm_k<0><<<dim3(HD / TS, (L_INP + TS - 1) / TS), blk, 0, stream>>>(
        W_enc, W_B, Wf, nullptr, nullptr, nullptr, L_INP, HD, MENC, MENC, 0, 0);
    gemm_k<0><<<dim3(HD / TS, 1), blk, 0, stream>>>(
        b_enc, W_B, bf, nullptr, nullptr, nullptr, 1, HD, MENC, MENC, 0, 0);
    gemm_k<1><<<dim3(HD / TS, MS / TS), blk, 0, stream>>>(
        x, Wf, Bu, bf, nullptr, nullptr, (int)MS, HD, L_INP, L_INP, 0, 0);

    // --- Powers: apw[i] = A^(i+1) via batched doubling ---
    copy4<<<dim3((int)(M2 / 4 / 256)), blk, 0, stream>>>(A, apw);
    // R1: apw[1] = A^2
    gemm_k<8><<<dim3(16, 16, 1), blk, 0, stream>>>(
        apw, apw + 0 * M2, apw, nullptr, nullptr, nullptr, HD, HD, HD, HD, 0, 1);
    // R2: apw[2,3] = apw[0,1]@A^2  (A^3, A^4)
    gemm_k<8><<<dim3(16, 16, 2), blk, 0, stream>>>(
        apw, apw + 1 * M2, apw, nullptr, nullptr, nullptr, HD, HD, HD, HD, 0, 2);
    // R3: apw[4..7] = apw[0..3]@A^4  (A^5..A^8)
    gemm_k<8><<<dim3(16, 16, 4), blk, 0, stream>>>(
        apw, apw + 3 * M2, apw, nullptr, nullptr, nullptr, HD, HD, HD, HD, 0, 4);
    // R4: apw[8..15] = apw[0..7]@A^8  (A^9..A^16)
    gemm_k<8><<<dim3(16, 16, 8), blk, 0, stream>>>(
        apw, apw + 7 * M2, apw, nullptr, nullptr, nullptr, HD, HD, HD, HD, 0, 8);
    // G = A^16 = apw[15]; GP[0] = A^32; GP[i] = GP[i-1]^2  (A^32..A^1024)
    gemm_k<0><<<dim3(16, 16), blk, 0, stream>>>(
        apw + 15 * M2, apw + 15 * M2, GP, nullptr, nullptr, nullptr, HD, HD, HD, HD, 0, 0);
    for (int i = 1; i < 6; ++i)
        gemm_k<0><<<dim3(16, 16), blk, 0, stream>>>(
            GP + (i - 1) * M2, GP + (i - 1) * M2, GP + i * M2, nullptr, nullptr, nullptr,
            HD, HD, HD, HD, 0, 0);

    // --- Pass 1: local chunk scans from zero; scatter ALL locals into Hout ---
    gather_bu<<<dim3(NROW * HD / 4 / 256), blk, 0, stream>>>(Bu, L0, Hout);
    float* cur = L0; float* nxt = L1;
    for (int t = 1; t < TCH; ++t) {
        gemm_k<6><<<dim3(HD / TS, NROW / TS), blk, 0, stream>>>(
            cur, A, nxt, nullptr, Bu, Hout, NROW, HD, HD, HD, t, 0);
        float* tmp = cur; cur = nxt; nxt = tmp;
    }
    float* Lend  = cur;                       // L1 (15 steps, odd)
    float* other = (Lend == L0) ? L1 : L0;    // L0

    // --- Prefix over chunk-end states: 7 Hillis-Steele rounds ---
    float* tgt[2] = { other, S0 };
    float* pin = Lend;
    for (int i = 0; i < 7; ++i) {
        int d = 1 << i;
        const float* Gm = (i == 0) ? (apw + 15 * M2) : (GP + (i - 1) * M2);
        gemm_k<5><<<dim3(HD / TS, NROW / TS), blk, 0, stream>>>(
            pin, Gm, tgt[i & 1], nullptr, pin, nullptr, NROW, HD, HD, HD, 0, d * BATCH);
        pin = tgt[i & 1];
    }
    float* Sfin = pin;   // state at end of each chunk c, rows c*16+b

    // --- Pass 3 (ONE launch): Hout[c,z] += E[c] @ A^(z+1), E[c] = Sfin[c-1] ---
    gemm_k<7><<<dim3(HD / TS, NROW / TS, TCH), blk, 0, stream>>>(
        Sfin, apw, nullptr, nullptr, nullptr, Hout, NROW, HD, HD, HD, 0, BATCH);

    // --- Last-token epilogue: residual, LN (double), MLP ---
    gemm_k<1><<<dim3(HD / TS, 1), blk, 0, stream>>>(
        x + (long)(SEQ - 1) * L_INP, W_res, Rlast, b_res, nullptr, nullptr,
        BATCH, HD, L_INP, SEQ * L_INP, 0, 0);
    ln_k<<<dim3(BATCH), blk, 0, stream>>>(Sfin, Rlast, ln_g, ln_b, zln);
    gemm_k<2><<<dim3(FM / TS, 1), blk, 0, stream>>>(
        zln, W1, t1, b1, nullptr, nullptr, BATCH, FM, HD, HD, 0, 0);
    gemm_k<1><<<dim3(HD / TS, 1), blk, 0, stream>>>(
        t1, W2, out0, b2, nullptr, nullptr, BATCH, HD, FM, FM, 0, 0);
}

// Round 4
// 2806.524 us; speedup vs baseline: 2.9851x; 1.8081x over previous
//
#include <hip/hip_runtime.h>
#include <math.h>

#define BATCH 16
#define SEQ   2048
#define L_INP 256
#define MENC  512
#define HD    1024
#define FM    4096
#define TCH   16
#define NCH   128
#define NROW  (BATCH*NCH)   // 2048 rows, row r = c*16 + b

typedef unsigned short u16;
typedef __attribute__((ext_vector_type(8))) short s8v;   // 8 bf16 (4 VGPRs)
typedef __attribute__((ext_vector_type(4))) float f4v;   // MFMA acc

__device__ inline u16 bf16_rne(float x) {
    unsigned u = __builtin_bit_cast(unsigned, x);
    u += 0x7fff + ((u >> 16) & 1);
    return (u16)(u >> 16);
}
__device__ inline float bf16_tof(u16 h) {
    unsigned u = ((unsigned)h) << 16;
    return __builtin_bit_cast(float, u);
}
__device__ inline void split2(float x, u16& h, u16& l) {
    h = bf16_rne(x);
    l = bf16_rne(x - bf16_tof(h));
}

// ---------------- fp32 tiled GEMM (encoder + tiny epilogue GEMMs) ----------------
#define TS 64
#define KT 16
#define LP 68
__device__ inline float4 add4(float4 a, float4 b) {
    return make_float4(a.x + b.x, a.y + b.y, a.z + b.z, a.w + b.w);
}
// MODE 0: OUT=IN@W   MODE 1: +bias   MODE 2: relu(+bias)
template<int MODE>
__global__ __launch_bounds__(256)
void gemm_k(const float* __restrict__ IN, const float* __restrict__ W,
            float* __restrict__ OUT, const float* __restrict__ BIAS,
            int M, int N, int K, int ldIN)
{
    __shared__ float As[KT][LP];
    __shared__ float Bs[KT][LP];
    const int tid  = threadIdx.x;
    const int tx   = tid & 15, ty = tid >> 4;
    const int col0 = blockIdx.x * TS;
    const int row0 = blockIdx.y * TS;
    const int la_k = tid & 15, la_r = tid >> 4;
    const int lb_j = tid & 63, lb_k = tid >> 6;
    float acc[4][4] = {};

    for (int k0 = 0; k0 < K; k0 += KT) {
        #pragma unroll
        for (int i = 0; i < 4; ++i) {
            int r = la_r + (i << 4);
            int grow = row0 + r;
            float v = 0.f;
            if (grow < M) v = IN[(long)grow * ldIN + k0 + la_k];
            As[la_k][r] = v;
        }
        #pragma unroll
        for (int i = 0; i < 4; ++i) {
            int k = lb_k + (i << 2);
            Bs[k][lb_j] = W[(long)(k0 + k) * N + col0 + lb_j];
        }
        __syncthreads();
        #pragma unroll
        for (int kk = 0; kk < KT; ++kk) {
            float4 av = *(const float4*)&As[kk][ty << 2];
            float4 bv = *(const float4*)&Bs[kk][tx << 2];
            float ar[4] = {av.x, av.y, av.z, av.w};
            float br[4] = {bv.x, bv.y, bv.z, bv.w};
            #pragma unroll
            for (int i = 0; i < 4; ++i)
                #pragma unroll
                for (int j = 0; j < 4; ++j)
                    acc[i][j] = fmaf(ar[i], br[j], acc[i][j]);
        }
        __syncthreads();
    }
    const int jc = col0 + (tx << 2);
    float4 bias4 = make_float4(0.f, 0.f, 0.f, 0.f);
    if constexpr (MODE == 1 || MODE == 2) bias4 = *(const float4*)&BIAS[jc];
    #pragma unroll
    for (int i = 0; i < 4; ++i) {
        int row = row0 + (ty << 2) + i;
        if (row >= M) continue;
        float4 vv = make_float4(acc[i][0], acc[i][1], acc[i][2], acc[i][3]);
        if constexpr (MODE == 1 || MODE == 2) vv = add4(vv, bias4);
        if constexpr (MODE == 2) {
            vv.x = fmaxf(vv.x, 0.f); vv.y = fmaxf(vv.y, 0.f);
            vv.z = fmaxf(vv.z, 0.f); vv.w = fmaxf(vv.w, 0.f);
        }
        *(float4*)&OUT[(long)row * N + jc] = vv;
    }
}

// ---------------- bf16-pair MFMA GEMM: OUT = IN@W, K=N=1024 fixed ----------------
// IN pairs natural [m][k]; W pairs TRANSPOSED [n][k]. 128x128 tile, 256 thr.
// MODE 0 (POW):  IN slot (inslot+z), OUT slots (oslot+z): nat + transposed pairs.
// MODE 1 (STEP): Hout fuse: v = acc + Hout[pos(r,t)]; Hout=v; emit state pairs.
// MODE 2 (PFX):  row-shift dshift on IN; v = acc + EX[r] (pair-reconstructed); emit pairs.
// MODE 3 (P3):   row-shift 16; W slot z; Hout[pos(r,z)] += acc.
#define LR 40   // LDS row stride in u16 (80 B)
template<int MODE>
__global__ __launch_bounds__(256)
void pgemm(const u16* __restrict__ INh, const u16* __restrict__ INl,
           const u16* __restrict__ Wh,  const u16* __restrict__ Wl,
           float* __restrict__ HOUT,
           const u16* __restrict__ EXh, const u16* __restrict__ EXl,
           u16* __restrict__ Oh, u16* __restrict__ Ol,
           u16* __restrict__ OTh, u16* __restrict__ OTl,
           int t, int dshift, int inslot, int oslot)
{
    const int tid = threadIdx.x;
    const int z = blockIdx.z;
    if constexpr (MODE == 0) {
        long oin = ((long)(inslot + z)) << 20;
        INh += oin; INl += oin;
        long oo = ((long)(oslot + z)) << 20;
        Oh += oo; Ol += oo; OTh += oo; OTl += oo;
    }
    if constexpr (MODE == 3) {
        long ow = ((long)z) << 20;   // W slot z = A^(z+1)
        Wh += ow; Wl += ow;
    }
    const int row0 = blockIdx.y * 128;
    const int col0 = blockIdx.x * 128;

    __shared__ u16 sAh[128 * LR], sAl[128 * LR], sBh[128 * LR], sBl[128 * LR];

    const int lane = tid & 63;
    const int wv   = tid >> 6;
    const int wrow = (wv >> 1) << 6;
    const int wcol = (wv & 1) << 6;
    const int fl   = lane & 15;
    const int quad = lane >> 4;

    f4v acc[4][4] = {};

    for (int k0 = 0; k0 < 1024; k0 += 32) {
        __syncthreads();
        // stage A (IN) and B (W-transposed) hi/lo tiles: 128 rows x 32 k (bf16)
        #pragma unroll
        for (int it = 0; it < 2; ++it) {
            int idx = tid + (it << 8);          // 0..511
            int r = idx >> 2, q = idx & 3;
            int ls = r * LR + q * 8;
            int gr = row0 + r;
            if constexpr (MODE == 2 || MODE == 3) gr -= dshift;
            uint4 vh, vl;
            if ((MODE == 2 || MODE == 3) && gr < 0) {
                vh = make_uint4(0, 0, 0, 0); vl = vh;
            } else {
                long goff = ((long)gr << 10) + k0 + q * 8;
                vh = *(const uint4*)&INh[goff];
                vl = *(const uint4*)&INl[goff];
            }
            *(uint4*)&sAh[ls] = vh;
            *(uint4*)&sAl[ls] = vl;
            long woff = ((long)(col0 + r) << 10) + k0 + q * 8;
            *(uint4*)&sBh[ls] = *(const uint4*)&Wh[woff];
            *(uint4*)&sBl[ls] = *(const uint4*)&Wl[woff];
        }
        __syncthreads();
        // fragments
        s8v ah[4], al[4], bh[4], bl[4];
        #pragma unroll
        for (int mt = 0; mt < 4; ++mt) {
            int r = wrow + mt * 16 + fl;
            ah[mt] = *(const s8v*)&sAh[r * LR + quad * 8];
            al[mt] = *(const s8v*)&sAl[r * LR + quad * 8];
        }
        #pragma unroll
        for (int nt = 0; nt < 4; ++nt) {
            int c = wcol + nt * 16 + fl;
            bh[nt] = *(const s8v*)&sBh[c * LR + quad * 8];
            bl[nt] = *(const s8v*)&sBl[c * LR + quad * 8];
        }
        #pragma unroll
        for (int mt = 0; mt < 4; ++mt)
            #pragma unroll
            for (int nt = 0; nt < 4; ++nt) {
                acc[mt][nt] = __builtin_amdgcn_mfma_f32_16x16x32_bf16(ah[mt], bh[nt], acc[mt][nt], 0, 0, 0);
                acc[mt][nt] = __builtin_amdgcn_mfma_f32_16x16x32_bf16(ah[mt], bl[nt], acc[mt][nt], 0, 0, 0);
                acc[mt][nt] = __builtin_amdgcn_mfma_f32_16x16x32_bf16(al[mt], bh[nt], acc[mt][nt], 0, 0, 0);
            }
    }

    // epilogue: C/D layout col=lane&15, row=quad*4+reg
    #pragma unroll
    for (int mt = 0; mt < 4; ++mt) {
        #pragma unroll
        for (int nt = 0; nt < 4; ++nt) {
            #pragma unroll
            for (int reg = 0; reg < 4; ++reg) {
                int grow = row0 + wrow + mt * 16 + quad * 4 + reg;
                int gcol = col0 + wcol + nt * 16 + fl;
                float v = acc[mt][nt][reg];
                if constexpr (MODE == 0) {
                    u16 h, l; split2(v, h, l);
                    long o  = ((long)grow << 10) + gcol;
                    long ot = ((long)gcol << 10) + grow;
                    Oh[o] = h; Ol[o] = l;
                    OTh[ot] = h; OTl[ot] = l;
                } else if constexpr (MODE == 1) {
                    int b = grow & 15, c = grow >> 4;
                    long exoff = ((long)(b * SEQ + c * TCH + t) << 10) + gcol;
                    v += HOUT[exoff];
                    HOUT[exoff] = v;
                    long o = ((long)grow << 10) + gcol;
                    u16 h, l; split2(v, h, l);
                    Oh[o] = h; Ol[o] = l;
                } else if constexpr (MODE == 2) {
                    long o = ((long)grow << 10) + gcol;
                    v += bf16_tof(EXh[o]) + bf16_tof(EXl[o]);
                    u16 h, l; split2(v, h, l);
                    Oh[o] = h; Ol[o] = l;
                } else {  // P3
                    if (grow >= 16) {
                        int b = grow & 15, c = grow >> 4;
                        long exoff = ((long)(b * SEQ + c * TCH + z) << 10) + gcol;
                        HOUT[exoff] += v;
                    }
                }
            }
        }
    }
}

// split A (input matrix) into nat pairs [m][k] and transposed pairs [n][k], slot 0
__global__ __launch_bounds__(256)
void splitA_k(const float* __restrict__ A, u16* __restrict__ nH, u16* __restrict__ nL,
              u16* __restrict__ tH, u16* __restrict__ tL)
{
    __shared__ unsigned sm[64][65];
    const int r0 = blockIdx.y * 64, c0 = blockIdx.x * 64;
    const int tr = threadIdx.x >> 4;
    const int tc = (threadIdx.x & 15) * 4;
    #pragma unroll
    for (int i = 0; i < 4; ++i) {
        int row = tr + i * 16;
        float4 v = *(const float4*)&A[((long)(r0 + row) << 10) + c0 + tc];
        float vv[4] = {v.x, v.y, v.z, v.w};
        u16 h[4], l[4];
        #pragma unroll
        for (int j = 0; j < 4; ++j) {
            split2(vv[j], h[j], l[j]);
            sm[row][tc + j] = (((unsigned)h[j]) << 16) | l[j];
        }
        long o = ((long)(r0 + row) << 10) + c0 + tc;
        *(uint2*)&nH[o] = make_uint2((unsigned)h[0] | ((unsigned)h[1] << 16),
                                     (unsigned)h[2] | ((unsigned)h[3] << 16));
        *(uint2*)&nL[o] = make_uint2((unsigned)l[0] | ((unsigned)l[1] << 16),
                                     (unsigned)l[2] | ((unsigned)l[3] << 16));
    }
    __syncthreads();
    #pragma unroll
    for (int i = 0; i < 4; ++i) {
        int n = tr + i * 16;
        unsigned p[4];
        #pragma unroll
        for (int j = 0; j < 4; ++j) p[j] = sm[tc + j][n];
        long o = ((long)(c0 + n) << 10) + r0 + tc;
        *(uint2*)&tH[o] = make_uint2((p[0] >> 16) | (p[1] & 0xffff0000u),
                                     (p[2] >> 16) | (p[3] & 0xffff0000u));
        *(uint2*)&tL[o] = make_uint2((p[0] & 0xffffu) | (p[1] << 16),
                                     (p[2] & 0xffffu) | (p[3] << 16));
    }
}

// L0 pairs = split(Hout[b, c*TCH])  (Hout holds bu)
__global__ __launch_bounds__(256)
void gather_bu_p(const float* __restrict__ Hout, u16* __restrict__ Oh, u16* __restrict__ Ol)
{
    long i = (long)blockIdx.x * 256 + threadIdx.x;  // 0 .. 2M
    int r = (int)(i >> 10), col = (int)(i & 1023);
    int b = r & 15, c = r >> 4;
    float v = Hout[((long)(b * SEQ + c * TCH) << 10) + col];
    u16 h, l; split2(v, h, l);
    Oh[i] = h; Ol[i] = l;
}

// LayerNorm in double over z = h_last + residual_last (z^2 ~ 1e54 overflows fp32)
__global__ __launch_bounds__(256)
void ln_k(const u16* __restrict__ Sh, const u16* __restrict__ Sl,
          const float* __restrict__ Rlast,
          const float* __restrict__ g, const float* __restrict__ bta,
          float* __restrict__ zout)
{
    __shared__ double red[256];
    int b = blockIdx.x, tid = threadIdx.x;
    long base = ((long)((NCH - 1) * BATCH + b)) << 10;
    const float* rr = Rlast + b * HD;
    double s = 0.0;
    for (int j = tid; j < HD; j += 256)
        s += (double)(bf16_tof(Sh[base + j]) + bf16_tof(Sl[base + j])) + (double)rr[j];
    red[tid] = s; __syncthreads();
    for (int o = 128; o > 0; o >>= 1) { if (tid < o) red[tid] += red[tid + o]; __syncthreads(); }
    double mu = red[0] * (1.0 / HD);
    __syncthreads();
    double ss = 0.0;
    for (int j = tid; j < HD; j += 256) {
        double zz = (double)(bf16_tof(Sh[base + j]) + bf16_tof(Sl[base + j])) + (double)rr[j] - mu;
        ss += zz * zz;
    }
    red[tid] = ss; __syncthreads();
    for (int o = 128; o > 0; o >>= 1) { if (tid < o) red[tid] += red[tid + o]; __syncthreads(); }
    double inv = 1.0 / sqrt(red[0] * (1.0 / HD) + 1e-5);
    __syncthreads();
    for (int j = tid; j < HD; j += 256) {
        double zz = (double)(bf16_tof(Sh[base + j]) + bf16_tof(Sl[base + j])) + (double)rr[j];
        zout[b * HD + j] = (float)(((zz - mu) * inv) * (double)g[j] + (double)bta[j]);
    }
}

extern "C" void kernel_launch(void* const* d_in, const int* in_sizes, int n_in,
                              void* d_out, int out_size, void* d_ws, size_t ws_size,
                              hipStream_t stream)
{
    const float* x     = (const float*)d_in[0];
    const float* W_enc = (const float*)d_in[1];
    const float* b_enc = (const float*)d_in[2];
    const float* W_B   = (const float*)d_in[3];
    const float* A     = (const float*)d_in[4];
    const float* W_res = (const float*)d_in[5];
    const float* b_res = (const float*)d_in[6];
    const float* ln_g  = (const float*)d_in[7];
    const float* ln_b  = (const float*)d_in[8];
    const float* W1    = (const float*)d_in[9];
    const float* b1    = (const float*)d_in[10];
    const float* W2    = (const float*)d_in[11];
    const float* b2    = (const float*)d_in[12];

    float* out0 = (float*)d_out;
    float* Hout = out0 + (long)BATCH * HD;     // (16,2048,1024): holds bu, then H_seq_pre

    // workspace carve (~205 MB)
    char* p = (char*)d_ws;
    auto alloc = [&](size_t bytes) { void* r = (void*)p; p += (bytes + 255) & ~(size_t)255; return r; };
    const long M2 = 1L << 20;                  // elements per power slot
    u16* natH = (u16*)alloc(22 * M2 * 2);      // slots 0..15: A^1..A^16; 16..21: A^32..A^1024
    u16* natL = (u16*)alloc(22 * M2 * 2);
    u16* trH  = (u16*)alloc(22 * M2 * 2);
    u16* trL  = (u16*)alloc(22 * M2 * 2);
    const long SB = (long)NROW * HD;           // 2M state elements
    u16* SPh[3]; u16* SPl[3];
    for (int i = 0; i < 3; ++i) { SPh[i] = (u16*)alloc(SB * 2); SPl[i] = (u16*)alloc(SB * 2); }
    float* Wf    = (float*)alloc((long)L_INP * HD * 4);
    float* bf    = (float*)alloc(HD * 4);
    float* Rlast = (float*)alloc(BATCH * HD * 4);
    float* zln   = (float*)alloc(BATCH * HD * 4);
    float* t1    = (float*)alloc((long)BATCH * FM * 4);

    dim3 blk(256);
    const long MS = (long)BATCH * SEQ;  // 32768

    // --- Encoder (fp32): Hout = x @ (W_enc@W_B) + b_enc@W_B   (= Bu) ---
    gemm_k<0><<<dim3(HD / TS, L_INP / TS), blk, 0, stream>>>(W_enc, W_B, Wf, nullptr, L_INP, HD, MENC, MENC);
    gemm_k<0><<<dim3(HD / TS, 1), blk, 0, stream>>>(b_enc, W_B, bf, nullptr, 1, HD, MENC, MENC);
    gemm_k<1><<<dim3(HD / TS, MS / TS), blk, 0, stream>>>(x, Wf, Hout, bf, (int)MS, HD, L_INP, L_INP);

    // --- split A into slot 0 ---
    splitA_k<<<dim3(16, 16), blk, 0, stream>>>(A, natH, natL, trH, trL);

    // --- powers via pair-MFMA doubling: slot s = A^(s+1) ---
    // R1: slot1 = slot0 @ A^1
    pgemm<0><<<dim3(8, 8, 1), blk, 0, stream>>>(natH, natL, trH, trL, nullptr, nullptr, nullptr,
                                                natH, natL, trH, trL, 0, 0, 0, 1);
    // R2: slots2,3 = slots0,1 @ A^2
    pgemm<0><<<dim3(8, 8, 2), blk, 0, stream>>>(natH, natL, trH + (1L << 20), trL + (1L << 20), nullptr, nullptr, nullptr,
                                                natH, natL, trH, trL, 0, 0, 0, 2);
    // R3: slots4..7 = slots0..3 @ A^4
    pgemm<0><<<dim3(8, 8, 4), blk, 0, stream>>>(natH, natL, trH + (3L << 20), trL + (3L << 20), nullptr, nullptr, nullptr,
                                                natH, natL, trH, trL, 0, 0, 0, 4);
    // R4: slots8..15 = slots0..7 @ A^8
    pgemm<0><<<dim3(8, 8, 8), blk, 0, stream>>>(natH, natL, trH + (7L << 20), trL + (7L << 20), nullptr, nullptr, nullptr,
                                                natH, natL, trH, trL, 0, 0, 0, 8);
    // G-chain: slot16 = A^32 = slot15@slot15; slot16+i = (slot15+i)^2
    for (int i = 0; i < 6; ++i) {
        int src = 15 + i;
        pgemm<0><<<dim3(8, 8, 1), blk, 0, stream>>>(natH, natL, trH + ((long)src << 20), trL + ((long)src << 20),
                                                    nullptr, nullptr, nullptr,
                                                    natH, natL, trH, trL, 0, 0, src, src + 1);
    }

    // --- Pass 1: local chunk scans (states as pairs), fused +bu / Hout scatter ---
    gather_bu_p<<<dim3((int)(SB / 256)), blk, 0, stream>>>(Hout, SPh[0], SPl[0]);
    int cur = 0, nxt = 1;
    for (int t = 1; t < TCH; ++t) {
        pgemm<1><<<dim3(8, 16), blk, 0, stream>>>(SPh[cur], SPl[cur], trH, trL, Hout, nullptr, nullptr,
                                                  SPh[nxt], SPl[nxt], nullptr, nullptr, t, 0, 0, 0);
        int tmp = cur; cur = nxt; nxt = tmp;
    }
    // cur == 1 after 15 steps

    // --- Prefix (7 Hillis-Steele rounds over chunk-end states) ---
    int pin = cur;            // buffer 1
    int tgt[2] = { nxt, 2 };  // {0, 2}
    for (int i = 0; i < 7; ++i) {
        int d = (1 << i) * BATCH;
        int wslot = (i == 0) ? 15 : (16 + i - 1);
        int ob = tgt[i & 1];
        pgemm<2><<<dim3(8, 16), blk, 0, stream>>>(SPh[pin], SPl[pin],
                                                  trH + ((long)wslot << 20), trL + ((long)wslot << 20),
                                                  nullptr, SPh[pin], SPl[pin],
                                                  SPh[ob], SPl[ob], nullptr, nullptr, 0, d, 0, 0);
        pin = ob;
    }
    int Sfin = pin;   // buffer 0 after 7 rounds

    // --- Pass 3 (one launch): Hout[c,z] += Sfin[c-1] @ A^(z+1) ---
    pgemm<3><<<dim3(8, 16, TCH), blk, 0, stream>>>(SPh[Sfin], SPl[Sfin], trH, trL, Hout, nullptr, nullptr,
                                                   nullptr, nullptr, nullptr, nullptr, 0, BATCH, 0, 0);

    // --- Last-token epilogue ---
    gemm_k<1><<<dim3(HD / TS, 1), blk, 0, stream>>>(x + (long)(SEQ - 1) * L_INP, W_res, Rlast, b_res,
                                                    BATCH, HD, L_INP, SEQ * L_INP);
    ln_k<<<dim3(BATCH), blk, 0, stream>>>(SPh[Sfin], SPl[Sfin], Rlast, ln_g, ln_b, zln);
    gemm_k<2><<<dim3(FM / TS, 1), blk, 0, stream>>>(zln, W1, t1, b1, BATCH, FM, HD, HD);
    gemm_k<1><<<dim3(HD / TS, 1), blk, 0, stream>>>(t1, W2, out0, b2, BATCH, HD, FM, FM);
}